// Round 13
// baseline (295.856 us; speedup 1.0000x reference)
//
#include <hip/hip_runtime.h>
#include <math.h>

#define NNODES 50000
#define NEDGES 400000
#define INC    128
#define HC1    256   // HEADS*HID
#define NHEADS 8
#define OUTC   64
#define NK     16
#define NEG_SLOPE 0.2f
#define EPS_F  1e-16f

typedef unsigned short u16;
typedef __attribute__((ext_vector_type(8))) short bf16x8;
typedef __attribute__((ext_vector_type(4))) float f32x4;

__device__ __forceinline__ float lrelu(float x){ return x > 0.f ? x : NEG_SLOPE * x; }
__device__ __forceinline__ float eluf(float x){ return x > 0.f ? x : (expf(x) - 1.f); }
__device__ __forceinline__ float bf2f(u16 v){ return __uint_as_float((unsigned)v << 16); }
__device__ __forceinline__ u16 f2bf(float f){
    unsigned u = __float_as_uint(f);
    unsigned r = (u + 0x7FFFu + ((u >> 16) & 1u)) >> 16;   // RTNE
    return (u16)r;
}
__device__ __forceinline__ short f2bf_s(float f){ return (short)f2bf(f); }

// ---------------- CSR build + weight prep ----------------
#define EB 1563   // ceil(400000/256)
#define TB 232    // ceil(59392/256)
__global__ void count_deg_tw_k(const int* __restrict__ dst, int* __restrict__ deg,
                               const float* __restrict__ W1, u16* __restrict__ W1t,
                               const float* __restrict__ W2, u16* __restrict__ W2t,
                               const float* __restrict__ Wm1, u16* __restrict__ W1mt,
                               const float* __restrict__ Wm2, u16* __restrict__ W2mt){
    if (blockIdx.x < EB){
        int e = blockIdx.x * 256 + threadIdx.x;
        if (e < NEDGES) atomicAdd(&deg[dst[e]], 1);
    } else {
        int i = (blockIdx.x - EB) * 256 + threadIdx.x;   // < 59392
        if (i < 32768){
            int n = i >> 7, k = i & 127;
            W1t[i] = f2bf(W1[k * 256 + n]);
        } else if (i < 49152){
            int ii = i - 32768;
            int n = ii >> 8, k = ii & 255;
            W2t[ii] = f2bf(W2[k * 64 + n]);
        } else if (i < 57344){
            int ii = i - 49152;
            int hd = ii >> 6, e = ii & 63;
            W1mt[ii] = f2bf(Wm1[e * 128 + hd]);
        } else if (i < 59392){
            int ii = i - 57344;
            int k = ii >> 7, hd = ii & 127;
            W2mt[ii] = f2bf(Wm2[hd * NK + k]);
        }
    }
}

__global__ void blocksum_k(const int* __restrict__ deg, int* __restrict__ bsum){
    __shared__ int sm[4];
    int i = blockIdx.x * 256 + threadIdx.x;
    int v = (i < NNODES) ? deg[i] : 0;
    for (int off = 1; off < 64; off <<= 1) v += __shfl_xor(v, off);
    int lane = threadIdx.x & 63, wid = threadIdx.x >> 6;
    if (lane == 0) sm[wid] = v;
    __syncthreads();
    if (threadIdx.x == 0) bsum[blockIdx.x] = sm[0] + sm[1] + sm[2] + sm[3];
}

__global__ void scan_write_k(const int* __restrict__ deg, const int* __restrict__ bsum,
                             int* __restrict__ rowptr){
    __shared__ int sm[4];
    __shared__ int sadd;
    int tid = threadIdx.x;
    int pv = (tid < blockIdx.x) ? bsum[tid] : 0;   // NB=196 < 256
    for (int off = 1; off < 64; off <<= 1) pv += __shfl_xor(pv, off);
    int lane = tid & 63, wid = tid >> 6;
    if (lane == 0) sm[wid] = pv;
    __syncthreads();
    if (tid == 0) sadd = sm[0] + sm[1] + sm[2] + sm[3];
    __syncthreads();

    int i = blockIdx.x * 256 + tid;
    int v = (i < NNODES) ? deg[i] : 0;
    int sv = v;
    for (int off = 1; off < 64; off <<= 1){ int t = __shfl_up(sv, off); if (lane >= off) sv += t; }
    __shared__ int wsum[4];
    if (lane == 63) wsum[wid] = sv;
    __syncthreads();
    int add = sadd;
    for (int w = 0; w < wid; w++) add += wsum[w];
    sv += add;
    if (i < NNODES) rowptr[i + 1] = sv;
    if (i == 0) rowptr[0] = 0;
}

__global__ void fill_csr_k(const int* __restrict__ src, const int* __restrict__ dst,
                           const int* __restrict__ rowptr, int* __restrict__ fillc,
                           int* __restrict__ col){
    int e = blockIdx.x * 256 + threadIdx.x;
    if (e < NEDGES){
        int d = dst[e];
        int pos = atomicAdd(&fillc[d], 1);
        col[rowptr[d] + pos] = src[e];
    }
}

// ---------------- L1: h1b[N,256] = bf16(x) @ W1, fused att1 (split over grid.y=2) ------
__global__ void l1_k(const float* __restrict__ x, const u16* __restrict__ W1t,
                     const float* __restrict__ att_s, const float* __restrict__ att_d,
                     u16* __restrict__ h1b, float* __restrict__ as1, float* __restrict__ ad1){
    int lane = threadIdx.x & 63, wid = threadIdx.x >> 6;
    int ln = lane & 15, quad = lane >> 4;
    int m0 = blockIdx.x * 64 + wid * 16;
    int nb = blockIdx.y * 128;
    int hb = blockIdx.y * 4;
    int arow = m0 + ln; if (arow >= NNODES) arow = NNODES - 1;

    bf16x8 a[4];
#pragma unroll
    for (int kt = 0; kt < 4; kt++){
        const float* ap = x + (size_t)arow * INC + kt * 32 + quad * 8;
        float4 v0 = *(const float4*)ap;
        float4 v1 = *(const float4*)(ap + 4);
        bf16x8 t;
        t[0] = f2bf_s(v0.x); t[1] = f2bf_s(v0.y); t[2] = f2bf_s(v0.z); t[3] = f2bf_s(v0.w);
        t[4] = f2bf_s(v1.x); t[5] = f2bf_s(v1.y); t[6] = f2bf_s(v1.z); t[7] = f2bf_s(v1.w);
        a[kt] = t;
    }

    f32x4 acc[8];
#pragma unroll
    for (int nt = 0; nt < 8; nt++) acc[nt] = (f32x4){0.f, 0.f, 0.f, 0.f};

#pragma unroll
    for (int kt = 0; kt < 4; kt++){
#pragma unroll
        for (int nt = 0; nt < 8; nt++){
            bf16x8 b = *(const bf16x8*)(W1t + (size_t)(nb + nt * 16 + ln) * INC + kt * 32 + quad * 8);
            acc[nt] = __builtin_amdgcn_mfma_f32_16x16x32_bf16(a[kt], b, acc[nt], 0, 0, 0);
        }
    }

#pragma unroll
    for (int i = 0; i < 4; i++){
        int r = m0 + quad * 4 + i;
        if (r < NNODES){
#pragma unroll
            for (int nt = 0; nt < 8; nt++)
                h1b[(size_t)r * HC1 + nb + nt * 16 + ln] = f2bf(acc[nt][i]);
        }
    }

#pragma unroll
    for (int i = 0; i < 4; i++){
        int r = m0 + quad * 4 + i;
        float ps_keep = 0.f, pd_keep = 0.f;
#pragma unroll
        for (int h = 0; h < 4; h++){
            float ps = acc[2 * h][i]     * att_s[nb + h * 32 + ln]
                     + acc[2 * h + 1][i] * att_s[nb + h * 32 + 16 + ln];
            float pd = acc[2 * h][i]     * att_d[nb + h * 32 + ln]
                     + acc[2 * h + 1][i] * att_d[nb + h * 32 + 16 + ln];
            ps += __shfl_xor(ps, 1); pd += __shfl_xor(pd, 1);
            ps += __shfl_xor(ps, 2); pd += __shfl_xor(pd, 2);
            ps += __shfl_xor(ps, 4); pd += __shfl_xor(pd, 4);
            ps += __shfl_xor(ps, 8); pd += __shfl_xor(pd, 8);
            if (ln == h){ ps_keep = ps; pd_keep = pd; }
        }
        if (ln < 4 && r < NNODES){
            as1[r * NHEADS + hb + ln] = ps_keep;
            ad1[r * NHEADS + hb + ln] = pd_keep;
        }
    }
}

// ---------------- L2: h2b[N,64] = hL1b @ W2, fused att2 ----------------
__global__ void l2_k(const u16* __restrict__ hL1b, const u16* __restrict__ W2t,
                     const float* __restrict__ att_s, const float* __restrict__ att_d,
                     u16* __restrict__ h2b, float* __restrict__ as2, float* __restrict__ ad2){
    int lane = threadIdx.x & 63, wid = threadIdx.x >> 6;
    int ln = lane & 15, quad = lane >> 4;
    int m0 = blockIdx.x * 64 + wid * 16;
    int arow = m0 + ln; if (arow >= NNODES) arow = NNODES - 1;

    f32x4 acc[4];
#pragma unroll
    for (int nt = 0; nt < 4; nt++) acc[nt] = (f32x4){0.f, 0.f, 0.f, 0.f};

#pragma unroll
    for (int kt = 0; kt < 8; kt++){
        bf16x8 a = *(const bf16x8*)(hL1b + (size_t)arow * HC1 + kt * 32 + quad * 8);
#pragma unroll
        for (int nt = 0; nt < 4; nt++){
            bf16x8 b = *(const bf16x8*)(W2t + (size_t)(nt * 16 + ln) * HC1 + kt * 32 + quad * 8);
            acc[nt] = __builtin_amdgcn_mfma_f32_16x16x32_bf16(a, b, acc[nt], 0, 0, 0);
        }
    }

#pragma unroll
    for (int i = 0; i < 4; i++){
        int r = m0 + quad * 4 + i;
        if (r < NNODES){
#pragma unroll
            for (int nt = 0; nt < 4; nt++)
                h2b[(size_t)r * OUTC + nt * 16 + ln] = f2bf(acc[nt][i]);
        }
        float ps = acc[0][i] * att_s[ln]      + acc[1][i] * att_s[16 + ln]
                 + acc[2][i] * att_s[32 + ln] + acc[3][i] * att_s[48 + ln];
        float pd = acc[0][i] * att_d[ln]      + acc[1][i] * att_d[16 + ln]
                 + acc[2][i] * att_d[32 + ln] + acc[3][i] * att_d[48 + ln];
        ps += __shfl_xor(ps, 1); pd += __shfl_xor(pd, 1);
        ps += __shfl_xor(ps, 2); pd += __shfl_xor(pd, 2);
        ps += __shfl_xor(ps, 4); pd += __shfl_xor(pd, 4);
        ps += __shfl_xor(ps, 8); pd += __shfl_xor(pd, 8);
        if (ln == 0 && r < NNODES){ as2[r] = ps; ad2[r] = pd; }
    }
}

// ---------------- gat1 helpers ----------------
// scores (phases 1-2, R8 formulas): outputs register cv[8], normalized ex[8], self alpha
__device__ __forceinline__ void gat1_scores(int d, int row0, int deg, int j, int h8,
                                            const float* __restrict__ as1,
                                            const float* __restrict__ ad1,
                                            const int* __restrict__ col,
                                            int cv[8], float ex[8], float& sa){
    float adst      = ad1[d * NHEADS + h8];
    float asrc_self = as1[d * NHEADS + h8];
    float e_self = lrelu(asrc_self + adst);
    int nch = (deg + 7) >> 3;

    float vmax = e_self;
#pragma unroll
    for (int c = 0; c < 8; c++){
        if (c >= nch) break;
        int idx = c * 8 + j;
        cv[c] = (idx < deg) ? col[row0 + idx] : d;
        if (idx < deg){
            float e = lrelu(as1[cv[c] * NHEADS + h8] + adst);
            ex[c] = e;
            vmax = fmaxf(vmax, e);
        } else ex[c] = -3e38f;
    }
    vmax = fmaxf(vmax, __shfl_xor(vmax, 8));
    vmax = fmaxf(vmax, __shfl_xor(vmax, 16));
    vmax = fmaxf(vmax, __shfl_xor(vmax, 32));

    float vsum = (j == 0) ? expf(e_self - vmax) : 0.f;
#pragma unroll
    for (int c = 0; c < 8; c++){
        if (c >= nch) break;
        float t = (ex[c] > -1e37f) ? expf(ex[c] - vmax) : 0.f;
        ex[c] = t;
        vsum += t;
    }
    vsum += __shfl_xor(vsum, 8);
    vsum += __shfl_xor(vsum, 16);
    vsum += __shfl_xor(vsum, 32);
    float rden = 1.f / (vsum + EPS_F);
#pragma unroll
    for (int c = 0; c < 8; c++){
        if (c >= nch) break;
        ex[c] *= rden;
    }
    sa = expf(e_self - vmax) * rden;
}

__device__ __forceinline__ void gat1_fma8(float acc[8], float a, uint4 w){
    acc[0] += a * __uint_as_float(w.x << 16);
    acc[1] += a * __uint_as_float(w.x & 0xFFFF0000u);
    acc[2] += a * __uint_as_float(w.y << 16);
    acc[3] += a * __uint_as_float(w.y & 0xFFFF0000u);
    acc[4] += a * __uint_as_float(w.z << 16);
    acc[5] += a * __uint_as_float(w.z & 0xFFFF0000u);
    acc[6] += a * __uint_as_float(w.w << 16);
    acc[7] += a * __uint_as_float(w.w & 0xFFFF0000u);
}

// general-degree single-node fallback (R8 legacy path; correct for any deg)
__device__ void gat1_node_legacy(int d, int row0, int deg, int lane,
                                 const u16* __restrict__ h1b, const float* __restrict__ as1,
                                 const float* __restrict__ ad1, const int* __restrict__ col,
                                 const float* __restrict__ b1, u16* __restrict__ outb){
    int h8 = lane & 7, j = lane >> 3;
    float adst      = ad1[d * NHEADS + h8];
    float asrc_self = as1[d * NHEADS + h8];
    float e_self = lrelu(asrc_self + adst);

    float vmax = e_self;
    for (int base = 0; base < deg; base += 8){
        int idx = base + j;
        if (idx < deg){
            int s = col[row0 + idx];
            vmax = fmaxf(vmax, lrelu(as1[s * NHEADS + h8] + adst));
        }
    }
    vmax = fmaxf(vmax, __shfl_xor(vmax, 8));
    vmax = fmaxf(vmax, __shfl_xor(vmax, 16));
    vmax = fmaxf(vmax, __shfl_xor(vmax, 32));

    float vsum = (j == 0) ? expf(e_self - vmax) : 0.f;
    for (int base = 0; base < deg; base += 8){
        int idx = base + j;
        if (idx < deg){
            int s = col[row0 + idx];
            vsum += expf(lrelu(as1[s * NHEADS + h8] + adst) - vmax);
        }
    }
    vsum += __shfl_xor(vsum, 8);
    vsum += __shfl_xor(vsum, 16);
    vsum += __shfl_xor(vsum, 32);
    float rden = 1.f / (vsum + EPS_F);

    int hw = lane >> 5, l32 = lane & 31, hd = l32 >> 2;
    float sa_reg = expf(e_self - vmax) * rden;
    float sa_b   = __shfl(sa_reg, hd);
    float asf    = hw ? 0.f : sa_b;

    float acc[8];
    {
        uint4 w = *(const uint4*)(h1b + (size_t)d * HC1 + l32 * 8);
#pragma unroll
        for (int k = 0; k < 8; k++) acc[k] = 0.f;
        gat1_fma8(acc, asf, w);
    }
    for (int base = 0; base < deg; base += 8){
        int eidx = base + j;
        int cj = (eidx < deg) ? col[row0 + eidx] : d;
        float ae = (eidx < deg)
                 ? expf(lrelu(as1[cj * NHEADS + h8] + adst) - vmax) * rden : 0.f;
#pragma unroll
        for (int st = 0; st < 4; st++){
            int it = st * 2 + hw;
            int s  = __shfl(cj, it * 8);
            float a = __shfl(ae, it * 8 + hd);
            uint4 w = *(const uint4*)(h1b + (size_t)s * HC1 + l32 * 8);
            gat1_fma8(acc, a, w);
        }
    }
#pragma unroll
    for (int k = 0; k < 8; k++) acc[k] += __shfl_xor(acc[k], 32);

    if (lane < 32){
        float4 b0 = *(const float4*)(b1 + l32 * 8);
        float4 b4 = *(const float4*)(b1 + l32 * 8 + 4);
        uint4 o;
        o.x = (unsigned)f2bf(eluf(acc[0] + b0.x)) | ((unsigned)f2bf(eluf(acc[1] + b0.y)) << 16);
        o.y = (unsigned)f2bf(eluf(acc[2] + b0.z)) | ((unsigned)f2bf(eluf(acc[3] + b0.w)) << 16);
        o.z = (unsigned)f2bf(eluf(acc[4] + b4.x)) | ((unsigned)f2bf(eluf(acc[5] + b4.y)) << 16);
        o.w = (unsigned)f2bf(eluf(acc[6] + b4.z)) | ((unsigned)f2bf(eluf(acc[7] + b4.w)) << 16);
        *(uint4*)(outb + (size_t)d * HC1 + l32 * 8) = o;
    }
}

// ---------------- GAT layer 1 aggregation: 2 independent nodes per wave ----------------
__global__ void gat1_agg_k(const u16* __restrict__ h1b, const float* __restrict__ as1,
                           const float* __restrict__ ad1, const int* __restrict__ rowptr,
                           const int* __restrict__ col, const float* __restrict__ b1,
                           u16* __restrict__ outb){
    int lane = threadIdx.x & 63, wid = threadIdx.x >> 6;
    int d0 = (blockIdx.x * 4 + wid) * 2;
    int d1 = d0 + 1;
    int row00 = rowptr[d0];
    int deg0  = rowptr[d0 + 1] - row00;
    int row01 = rowptr[d1];
    int deg1  = rowptr[d1 + 1] - row01;

    if (deg0 > 64 || deg1 > 64){
        gat1_node_legacy(d0, row00, deg0, lane, h1b, as1, ad1, col, b1, outb);
        gat1_node_legacy(d1, row01, deg1, lane, h1b, as1, ad1, col, b1, outb);
        return;
    }

    int h8 = lane & 7, j = lane >> 3;
    int cv0[8], cv1[8];
    float ex0[8], ex1[8];
    float sa0, sa1;
    gat1_scores(d0, row00, deg0, j, h8, as1, ad1, col, cv0, ex0, sa0);
    gat1_scores(d1, row01, deg1, j, h8, as1, ad1, col, cv1, ex1, sa1);

    int hw = lane >> 5, l32 = lane & 31, hd = l32 >> 2;
    float asf0 = hw ? 0.f : __shfl(sa0, hd);
    float asf1 = hw ? 0.f : __shfl(sa1, hd);

    float acc0[8], acc1[8];
#pragma unroll
    for (int k = 0; k < 8; k++){ acc0[k] = 0.f; acc1[k] = 0.f; }
    {
        uint4 w0 = *(const uint4*)(h1b + (size_t)d0 * HC1 + l32 * 8);
        uint4 w1 = *(const uint4*)(h1b + (size_t)d1 * HC1 + l32 * 8);
        gat1_fma8(acc0, asf0, w0);
        gat1_fma8(acc1, asf1, w1);
    }

    int nch0 = (deg0 + 7) >> 3, nch1 = (deg1 + 7) >> 3;
    int nchm = max(nch0, nch1);
#pragma unroll
    for (int c = 0; c < 8; c++){
        if (c >= nchm) break;
        bool v0 = (c < nch0), v1 = (c < nch1);
#pragma unroll
        for (int st = 0; st < 4; st++){
            int it = st * 2 + hw;
            if (v0){
                int s  = __shfl(cv0[c], it * 8);
                float a = __shfl(ex0[c], it * 8 + hd);
                uint4 w = *(const uint4*)(h1b + (size_t)s * HC1 + l32 * 8);
                gat1_fma8(acc0, a, w);
            }
            if (v1){
                int s  = __shfl(cv1[c], it * 8);
                float a = __shfl(ex1[c], it * 8 + hd);
                uint4 w = *(const uint4*)(h1b + (size_t)s * HC1 + l32 * 8);
                gat1_fma8(acc1, a, w);
            }
        }
    }
#pragma unroll
    for (int k = 0; k < 8; k++){
        acc0[k] += __shfl_xor(acc0[k], 32);
        acc1[k] += __shfl_xor(acc1[k], 32);
    }

    // node0 written by lanes 0-31, node1 by lanes 32-63 (same l32 channel mapping)
    float r[8];
#pragma unroll
    for (int k = 0; k < 8; k++) r[k] = (lane < 32) ? acc0[k] : acc1[k];
    int dd = (lane < 32) ? d0 : d1;
    float4 b0 = *(const float4*)(b1 + l32 * 8);
    float4 b4 = *(const float4*)(b1 + l32 * 8 + 4);
    uint4 o;
    o.x = (unsigned)f2bf(eluf(r[0] + b0.x)) | ((unsigned)f2bf(eluf(r[1] + b0.y)) << 16);
    o.y = (unsigned)f2bf(eluf(r[2] + b0.z)) | ((unsigned)f2bf(eluf(r[3] + b0.w)) << 16);
    o.z = (unsigned)f2bf(eluf(r[4] + b4.x)) | ((unsigned)f2bf(eluf(r[5] + b4.y)) << 16);
    o.w = (unsigned)f2bf(eluf(r[6] + b4.z)) | ((unsigned)f2bf(eluf(r[7] + b4.w)) << 16);
    *(uint4*)(outb + (size_t)dd * HC1 + l32 * 8) = o;
}

// ---------------- GAT layer 2 aggregation (4 gathers in flight) ----------------
__global__ void gat2_agg_k(const u16* __restrict__ h2b, const float* __restrict__ as2,
                           const float* __restrict__ ad2, const int* __restrict__ rowptr,
                           const int* __restrict__ col, const float* __restrict__ b2,
                           float* __restrict__ emb){
    int lane = threadIdx.x & 63, wid = threadIdx.x >> 6;
    int d = blockIdx.x * 4 + wid;
    int row0 = rowptr[d];
    int deg  = rowptr[d + 1] - row0;

    float adst = ad2[d];
    float e_self = lrelu(as2[d] + adst);

    if (deg <= 64){
        int sv = (lane < deg) ? col[row0 + lane] : d;
        float e_lane = (lane < deg) ? lrelu(as2[sv] + adst) : -3e38f;
        float vmax = fmaxf(e_self, e_lane);
        for (int m = 1; m < 64; m <<= 1) vmax = fmaxf(vmax, __shfl_xor(vmax, m));
        float exl = (lane < deg) ? expf(e_lane - vmax) : 0.f;
        float vsum = exl + ((lane == 0) ? expf(e_self - vmax) : 0.f);
        for (int m = 1; m < 64; m <<= 1) vsum += __shfl_xor(vsum, m);
        float rden = 1.f / (vsum + EPS_F);
        float alpha_l = exl * rden;
        float sa = expf(e_self - vmax) * rden;

        int q = lane >> 4, c4 = (lane & 15) * 4;
        float a0 = (q == 0) ? sa : 0.f;
        float4 acc;
        {
            ushort4 u = *(const ushort4*)(h2b + (size_t)d * OUTC + c4);
            acc = make_float4(a0 * bf2f(u.x), a0 * bf2f(u.y), a0 * bf2f(u.z), a0 * bf2f(u.w));
        }
        for (int it0 = 0; it0 < deg; it0 += 16){
            int s_arr[4]; float a_arr[4];
#pragma unroll
            for (int k = 0; k < 4; k++){
                int itc = min(it0 + k * 4 + q, 63);
                s_arr[k] = __shfl(sv, itc);
                a_arr[k] = __shfl(alpha_l, itc);
            }
            ushort4 u_arr[4];
#pragma unroll
            for (int k = 0; k < 4; k++)
                u_arr[k] = *(const ushort4*)(h2b + (unsigned)s_arr[k] * OUTC + c4);
#pragma unroll
            for (int k = 0; k < 4; k++){
                float a = a_arr[k]; ushort4 u = u_arr[k];
                acc.x += a * bf2f(u.x); acc.y += a * bf2f(u.y);
                acc.z += a * bf2f(u.z); acc.w += a * bf2f(u.w);
            }
        }
        acc.x += __shfl_xor(acc.x, 16); acc.y += __shfl_xor(acc.y, 16);
        acc.z += __shfl_xor(acc.z, 16); acc.w += __shfl_xor(acc.w, 16);
        acc.x += __shfl_xor(acc.x, 32); acc.y += __shfl_xor(acc.y, 32);
        acc.z += __shfl_xor(acc.z, 32); acc.w += __shfl_xor(acc.w, 32);
        if (lane < 16){
            float4 bb = *(const float4*)(b2 + c4);
            float4 o = make_float4(acc.x + bb.x, acc.y + bb.y, acc.z + bb.z, acc.w + bb.w);
            *(float4*)(emb + (size_t)d * OUTC + c4) = o;
        }
    } else {
        float vmax = e_self;
        for (int base = 0; base < deg; base += 64){
            int idx = base + lane;
            if (idx < deg){
                int s = col[row0 + idx];
                vmax = fmaxf(vmax, lrelu(as2[s] + adst));
            }
        }
        for (int m = 1; m < 64; m <<= 1) vmax = fmaxf(vmax, __shfl_xor(vmax, m));
        float vsum = (lane == 0) ? expf(e_self - vmax) : 0.f;
        for (int base = 0; base < deg; base += 64){
            int idx = base + lane;
            if (idx < deg){
                int s = col[row0 + idx];
                vsum += expf(lrelu(as2[s] + adst) - vmax);
            }
        }
        for (int m = 1; m < 64; m <<= 1) vsum += __shfl_xor(vsum, m);
        float rden = 1.f / (vsum + EPS_F);
        float alpha = expf(e_self - vmax) * rden;
        float acc = alpha * bf2f(h2b[(size_t)d * OUTC + lane]);
        for (int idx = 0; idx < deg; idx++){
            int s = col[row0 + idx];
            float a = expf(lrelu(as2[s] + adst) - vmax) * rden;
            acc += a * bf2f(h2b[(size_t)s * OUTC + lane]);
        }
        emb[(size_t)d * OUTC + lane] = acc + b2[lane];
    }
}

// ---------------- MLP head + softmax via MFMA ----------------
__global__ void mlp_mfma_k(const float* __restrict__ emb, const u16* __restrict__ W1mt,
                           const float* __restrict__ bm1, const u16* __restrict__ W2mt,
                           const float* __restrict__ bm2, float* __restrict__ sout){
    __shared__ u16 hid[4][16][136];
    int lane = threadIdx.x & 63, wid = threadIdx.x >> 6;
    int ln = lane & 15, quad = lane >> 4;
    int m0 = blockIdx.x * 64 + wid * 16;
    int arow = m0 + ln; if (arow >= NNODES) arow = NNODES - 1;

    bf16x8 a[2];
#pragma unroll
    for (int kt = 0; kt < 2; kt++){
        const float* ap = emb + (size_t)arow * OUTC + kt * 32 + quad * 8;
        float4 v0 = *(const float4*)ap;
        float4 v1 = *(const float4*)(ap + 4);
        bf16x8 t;
        t[0] = f2bf_s(v0.x); t[1] = f2bf_s(v0.y); t[2] = f2bf_s(v0.z); t[3] = f2bf_s(v0.w);
        t[4] = f2bf_s(v1.x); t[5] = f2bf_s(v1.y); t[6] = f2bf_s(v1.z); t[7] = f2bf_s(v1.w);
        a[kt] = t;
    }

    f32x4 acc[8];
#pragma unroll
    for (int nt = 0; nt < 8; nt++) acc[nt] = (f32x4){0.f, 0.f, 0.f, 0.f};
#pragma unroll
    for (int kt = 0; kt < 2; kt++){
#pragma unroll
        for (int nt = 0; nt < 8; nt++){
            bf16x8 b = *(const bf16x8*)(W1mt + (size_t)(nt * 16 + ln) * OUTC + kt * 32 + quad * 8);
            acc[nt] = __builtin_amdgcn_mfma_f32_16x16x32_bf16(a[kt], b, acc[nt], 0, 0, 0);
        }
    }

#pragma unroll
    for (int nt = 0; nt < 8; nt++){
        float bb = bm1[nt * 16 + ln];
#pragma unroll
        for (int i = 0; i < 4; i++){
            float h = fmaxf(acc[nt][i] + bb, 0.f);
            hid[wid][quad * 4 + i][nt * 16 + ln] = f2bf(h);
        }
    }

    f32x4 acc2 = (f32x4){0.f, 0.f, 0.f, 0.f};
#pragma unroll
    for (int kt = 0; kt < 4; kt++){
        bf16x8 ah = *(const bf16x8*)&hid[wid][ln][kt * 32 + quad * 8];
        bf16x8 bw = *(const bf16x8*)(W2mt + (size_t)ln * 128 + kt * 32 + quad * 8);
        acc2 = __builtin_amdgcn_mfma_f32_16x16x32_bf16(ah, bw, acc2, 0, 0, 0);
    }

    float bcl = bm2[ln];
#pragma unroll
    for (int i = 0; i < 4; i++){
        int r = m0 + quad * 4 + i;
        float lg = acc2[i] + bcl;
        float m = lg;
        m = fmaxf(m, __shfl_xor(m, 1));
        m = fmaxf(m, __shfl_xor(m, 2));
        m = fmaxf(m, __shfl_xor(m, 4));
        m = fmaxf(m, __shfl_xor(m, 8));
        float ex = expf(lg - m);
        float s = ex;
        s += __shfl_xor(s, 1);
        s += __shfl_xor(s, 2);
        s += __shfl_xor(s, 4);
        s += __shfl_xor(s, 8);
        if (r < NNODES) sout[(size_t)r * NK + ln] = ex / s;
    }
}

// ---------------- launcher ----------------
extern "C" void kernel_launch(void* const* d_in, const int* in_sizes, int n_in,
                              void* d_out, int out_size, void* d_ws, size_t ws_size,
                              hipStream_t stream){
    const float* x      = (const float*)d_in[0];
    const int*   ei     = (const int*)d_in[1];
    const int*   srcv   = ei;
    const int*   dstv   = ei + NEDGES;
    const float* W1     = (const float*)d_in[2];
    const float* att_s1 = (const float*)d_in[3];
    const float* att_d1 = (const float*)d_in[4];
    const float* b1     = (const float*)d_in[5];
    const float* W2     = (const float*)d_in[6];
    const float* att_s2 = (const float*)d_in[7];
    const float* att_d2 = (const float*)d_in[8];
    const float* b2     = (const float*)d_in[9];
    const float* Wm1    = (const float*)d_in[10];
    const float* bm1    = (const float*)d_in[11];
    const float* Wm2    = (const float*)d_in[12];
    const float* bm2    = (const float*)d_in[13];

    float* out     = (float*)d_out;                     // s: [N,16]
    float* emb_out = out + (size_t)NNODES * NK;         // embeddings: [N,64]

    u16* h1b   = (u16*)d_ws;                            // N*256
    u16* hL1b  = h1b  + (size_t)NNODES * HC1;           // N*256
    u16* h2b   = hL1b + (size_t)NNODES * HC1;           // N*64
    u16* W1t   = h2b  + (size_t)NNODES * OUTC;          // 256*128
    u16* W2t   = W1t + 256 * 128;                       // 64*256
    u16* W1mt  = W2t + 64 * 256;                        // 128*64
    u16* W2mt  = W1mt + 128 * 64;                       // 16*128
    float* as1 = (float*)(W2mt + 16 * 128);             // N*8
    float* ad1 = as1 + (size_t)NNODES * NHEADS;         // N*8
    float* as2 = ad1 + (size_t)NNODES * NHEADS;         // N
    float* ad2 = as2 + NNODES;                          // N
    int* deg    = (int*)(ad2 + NNODES);                 // N   (deg+fillc adjacent -> 1 memset)
    int* fillc  = deg + NNODES;                         // N
    int* rowptr = fillc + NNODES;                       // N+1
    int* bsum   = rowptr + NNODES + 1;                  // 256
    int* colv   = bsum + 256;                           // E

    hipMemsetAsync(deg, 0, 2 * NNODES * sizeof(int), stream);

    const int NB = (NNODES + 255) / 256;   // 196

    count_deg_tw_k<<<EB + TB, 256, 0, stream>>>(dstv, deg, W1, W1t, W2, W2t, Wm1, W1mt, Wm2, W2mt);
    blocksum_k<<<NB, 256, 0, stream>>>(deg, bsum);
    scan_write_k<<<NB, 256, 0, stream>>>(deg, bsum, rowptr);
    fill_csr_k<<<(NEDGES + 255) / 256, 256, 0, stream>>>(srcv, dstv, rowptr, fillc, colv);

    const int MB = (NNODES + 63) / 64;   // 782

    l1_k<<<dim3(MB, 2), 256, 0, stream>>>(x, W1t, att_s1, att_d1, h1b, as1, ad1);
    gat1_agg_k<<<NNODES / 8, 256, 0, stream>>>(h1b, as1, ad1, rowptr, colv, b1, hL1b);

    l2_k<<<MB, 256, 0, stream>>>(hL1b, W2t, att_s2, att_d2, h2b, as2, ad2);
    gat2_agg_k<<<NNODES / 4, 256, 0, stream>>>(h2b, as2, ad2, rowptr, colv, b2, emb_out);

    mlp_mfma_k<<<MB, 256, 0, stream>>>(emb_out, W1mt, bm1, W2mt, bm2, out);
}

// Round 14
// 290.445 us; speedup vs baseline: 1.0186x; 1.0186x over previous
//
#include <hip/hip_runtime.h>
#include <math.h>

#define NNODES 50000
#define NEDGES 400000
#define INC    128
#define HC1    256   // HEADS*HID
#define NHEADS 8
#define OUTC   64
#define NK     16
#define NEG_SLOPE 0.2f
#define EPS_F  1e-16f

typedef unsigned short u16;
typedef __attribute__((ext_vector_type(8))) short bf16x8;
typedef __attribute__((ext_vector_type(4))) float f32x4;

__device__ __forceinline__ float lrelu(float x){ return x > 0.f ? x : NEG_SLOPE * x; }
__device__ __forceinline__ float eluf(float x){ return x > 0.f ? x : (expf(x) - 1.f); }
__device__ __forceinline__ float bf2f(u16 v){ return __uint_as_float((unsigned)v << 16); }
__device__ __forceinline__ u16 f2bf(float f){
    unsigned u = __float_as_uint(f);
    unsigned r = (u + 0x7FFFu + ((u >> 16) & 1u)) >> 16;   // RTNE
    return (u16)r;
}
__device__ __forceinline__ short f2bf_s(float f){ return (short)f2bf(f); }

// ---------------- CSR build + weight prep ----------------
#define EB 1563   // ceil(400000/256)
#define TB 232    // ceil(59392/256)
__global__ void count_deg_tw_k(const int* __restrict__ dst, int* __restrict__ deg,
                               const float* __restrict__ W1, u16* __restrict__ W1t,
                               const float* __restrict__ W2, u16* __restrict__ W2t,
                               const float* __restrict__ Wm1, u16* __restrict__ W1mt,
                               const float* __restrict__ Wm2, u16* __restrict__ W2mt){
    if (blockIdx.x < EB){
        int e = blockIdx.x * 256 + threadIdx.x;
        if (e < NEDGES) atomicAdd(&deg[dst[e]], 1);
    } else {
        int i = (blockIdx.x - EB) * 256 + threadIdx.x;   // < 59392
        if (i < 32768){
            int n = i >> 7, k = i & 127;
            W1t[i] = f2bf(W1[k * 256 + n]);
        } else if (i < 49152){
            int ii = i - 32768;
            int n = ii >> 8, k = ii & 255;
            W2t[ii] = f2bf(W2[k * 64 + n]);
        } else if (i < 57344){
            int ii = i - 49152;
            int hd = ii >> 6, e = ii & 63;
            W1mt[ii] = f2bf(Wm1[e * 128 + hd]);
        } else if (i < 59392){
            int ii = i - 57344;
            int k = ii >> 7, hd = ii & 127;
            W2mt[ii] = f2bf(Wm2[hd * NK + k]);
        }
    }
}

__global__ void blocksum_k(const int* __restrict__ deg, int* __restrict__ bsum){
    __shared__ int sm[4];
    int i = blockIdx.x * 256 + threadIdx.x;
    int v = (i < NNODES) ? deg[i] : 0;
    for (int off = 1; off < 64; off <<= 1) v += __shfl_xor(v, off);
    int lane = threadIdx.x & 63, wid = threadIdx.x >> 6;
    if (lane == 0) sm[wid] = v;
    __syncthreads();
    if (threadIdx.x == 0) bsum[blockIdx.x] = sm[0] + sm[1] + sm[2] + sm[3];
}

__global__ void scan_write_k(const int* __restrict__ deg, const int* __restrict__ bsum,
                             int* __restrict__ rowptr){
    __shared__ int sm[4];
    __shared__ int sadd;
    int tid = threadIdx.x;
    int pv = (tid < blockIdx.x) ? bsum[tid] : 0;   // NB=196 < 256
    for (int off = 1; off < 64; off <<= 1) pv += __shfl_xor(pv, off);
    int lane = tid & 63, wid = tid >> 6;
    if (lane == 0) sm[wid] = pv;
    __syncthreads();
    if (tid == 0) sadd = sm[0] + sm[1] + sm[2] + sm[3];
    __syncthreads();

    int i = blockIdx.x * 256 + tid;
    int v = (i < NNODES) ? deg[i] : 0;
    int sv = v;
    for (int off = 1; off < 64; off <<= 1){ int t = __shfl_up(sv, off); if (lane >= off) sv += t; }
    __shared__ int wsum[4];
    if (lane == 63) wsum[wid] = sv;
    __syncthreads();
    int add = sadd;
    for (int w = 0; w < wid; w++) add += wsum[w];
    sv += add;
    if (i < NNODES) rowptr[i + 1] = sv;
    if (i == 0) rowptr[0] = 0;
}

__global__ void fill_csr_k(const int* __restrict__ src, const int* __restrict__ dst,
                           const int* __restrict__ rowptr, int* __restrict__ fillc,
                           int* __restrict__ col){
    int e = blockIdx.x * 256 + threadIdx.x;
    if (e < NEDGES){
        int d = dst[e];
        int pos = atomicAdd(&fillc[d], 1);
        col[rowptr[d] + pos] = src[e];
    }
}

// ---------------- L1: h1b[N,256] = bf16(x) @ W1, fused att1 (split over grid.y=2) ------
__global__ void l1_k(const float* __restrict__ x, const u16* __restrict__ W1t,
                     const float* __restrict__ att_s, const float* __restrict__ att_d,
                     u16* __restrict__ h1b, float* __restrict__ as1, float* __restrict__ ad1){
    int lane = threadIdx.x & 63, wid = threadIdx.x >> 6;
    int ln = lane & 15, quad = lane >> 4;
    int m0 = blockIdx.x * 64 + wid * 16;
    int nb = blockIdx.y * 128;            // col base: 0 or 128
    int hb = blockIdx.y * 4;              // head base: 0 or 4
    int arow = m0 + ln; if (arow >= NNODES) arow = NNODES - 1;

    bf16x8 a[4];
#pragma unroll
    for (int kt = 0; kt < 4; kt++){
        const float* ap = x + (size_t)arow * INC + kt * 32 + quad * 8;
        float4 v0 = *(const float4*)ap;
        float4 v1 = *(const float4*)(ap + 4);
        bf16x8 t;
        t[0] = f2bf_s(v0.x); t[1] = f2bf_s(v0.y); t[2] = f2bf_s(v0.z); t[3] = f2bf_s(v0.w);
        t[4] = f2bf_s(v1.x); t[5] = f2bf_s(v1.y); t[6] = f2bf_s(v1.z); t[7] = f2bf_s(v1.w);
        a[kt] = t;
    }

    f32x4 acc[8];
#pragma unroll
    for (int nt = 0; nt < 8; nt++) acc[nt] = (f32x4){0.f, 0.f, 0.f, 0.f};

#pragma unroll
    for (int kt = 0; kt < 4; kt++){
#pragma unroll
        for (int nt = 0; nt < 8; nt++){
            bf16x8 b = *(const bf16x8*)(W1t + (size_t)(nb + nt * 16 + ln) * INC + kt * 32 + quad * 8);
            acc[nt] = __builtin_amdgcn_mfma_f32_16x16x32_bf16(a[kt], b, acc[nt], 0, 0, 0);
        }
    }

#pragma unroll
    for (int i = 0; i < 4; i++){
        int r = m0 + quad * 4 + i;
        if (r < NNODES){
#pragma unroll
            for (int nt = 0; nt < 8; nt++)
                h1b[(size_t)r * HC1 + nb + nt * 16 + ln] = f2bf(acc[nt][i]);
        }
    }

#pragma unroll
    for (int i = 0; i < 4; i++){
        int r = m0 + quad * 4 + i;
        float ps_keep = 0.f, pd_keep = 0.f;
#pragma unroll
        for (int h = 0; h < 4; h++){
            float ps = acc[2 * h][i]     * att_s[nb + h * 32 + ln]
                     + acc[2 * h + 1][i] * att_s[nb + h * 32 + 16 + ln];
            float pd = acc[2 * h][i]     * att_d[nb + h * 32 + ln]
                     + acc[2 * h + 1][i] * att_d[nb + h * 32 + 16 + ln];
            ps += __shfl_xor(ps, 1); pd += __shfl_xor(pd, 1);
            ps += __shfl_xor(ps, 2); pd += __shfl_xor(pd, 2);
            ps += __shfl_xor(ps, 4); pd += __shfl_xor(pd, 4);
            ps += __shfl_xor(ps, 8); pd += __shfl_xor(pd, 8);
            if (ln == h){ ps_keep = ps; pd_keep = pd; }
        }
        if (ln < 4 && r < NNODES){
            as1[r * NHEADS + hb + ln] = ps_keep;
            ad1[r * NHEADS + hb + ln] = pd_keep;
        }
    }
}

// ---------------- L2: h2b[N,64] = hL1b @ W2, fused att2 ----------------
__global__ void l2_k(const u16* __restrict__ hL1b, const u16* __restrict__ W2t,
                     const float* __restrict__ att_s, const float* __restrict__ att_d,
                     u16* __restrict__ h2b, float* __restrict__ as2, float* __restrict__ ad2){
    int lane = threadIdx.x & 63, wid = threadIdx.x >> 6;
    int ln = lane & 15, quad = lane >> 4;
    int m0 = blockIdx.x * 64 + wid * 16;
    int arow = m0 + ln; if (arow >= NNODES) arow = NNODES - 1;

    f32x4 acc[4];
#pragma unroll
    for (int nt = 0; nt < 4; nt++) acc[nt] = (f32x4){0.f, 0.f, 0.f, 0.f};

#pragma unroll
    for (int kt = 0; kt < 8; kt++){
        bf16x8 a = *(const bf16x8*)(hL1b + (size_t)arow * HC1 + kt * 32 + quad * 8);
#pragma unroll
        for (int nt = 0; nt < 4; nt++){
            bf16x8 b = *(const bf16x8*)(W2t + (size_t)(nt * 16 + ln) * HC1 + kt * 32 + quad * 8);
            acc[nt] = __builtin_amdgcn_mfma_f32_16x16x32_bf16(a, b, acc[nt], 0, 0, 0);
        }
    }

#pragma unroll
    for (int i = 0; i < 4; i++){
        int r = m0 + quad * 4 + i;
        if (r < NNODES){
#pragma unroll
            for (int nt = 0; nt < 4; nt++)
                h2b[(size_t)r * OUTC + nt * 16 + ln] = f2bf(acc[nt][i]);
        }
        float ps = acc[0][i] * att_s[ln]      + acc[1][i] * att_s[16 + ln]
                 + acc[2][i] * att_s[32 + ln] + acc[3][i] * att_s[48 + ln];
        float pd = acc[0][i] * att_d[ln]      + acc[1][i] * att_d[16 + ln]
                 + acc[2][i] * att_d[32 + ln] + acc[3][i] * att_d[48 + ln];
        ps += __shfl_xor(ps, 1); pd += __shfl_xor(pd, 1);
        ps += __shfl_xor(ps, 2); pd += __shfl_xor(pd, 2);
        ps += __shfl_xor(ps, 4); pd += __shfl_xor(pd, 4);
        ps += __shfl_xor(ps, 8); pd += __shfl_xor(pd, 8);
        if (ln == 0 && r < NNODES){ as2[r] = ps; ad2[r] = pd; }
    }
}

// ---------------- GAT layer 1 aggregation (R8 version, best measured) ----------------
__global__ void gat1_agg_k(const u16* __restrict__ h1b, const float* __restrict__ as1,
                           const float* __restrict__ ad1, const int* __restrict__ rowptr,
                           const int* __restrict__ col, const float* __restrict__ b1,
                           u16* __restrict__ outb){
    int lane = threadIdx.x & 63, wid = threadIdx.x >> 6;
    int d = blockIdx.x * 4 + wid;
    int row0 = rowptr[d];
    int deg  = rowptr[d + 1] - row0;

    int h8 = lane & 7, j = lane >> 3;
    float adst      = ad1[d * NHEADS + h8];
    float asrc_self = as1[d * NHEADS + h8];
    float e_self = lrelu(asrc_self + adst);

    if (deg <= 64){
        int nch = (deg + 7) >> 3;
        int cv[8]; float ex[8];
        float vmax = e_self;
#pragma unroll
        for (int c = 0; c < 8; c++){
            if (c >= nch) break;
            int idx = c * 8 + j;
            cv[c] = (idx < deg) ? col[row0 + idx] : d;
            if (idx < deg){
                float e = lrelu(as1[cv[c] * NHEADS + h8] + adst);
                ex[c] = e;
                vmax = fmaxf(vmax, e);
            } else ex[c] = -3e38f;
        }
        vmax = fmaxf(vmax, __shfl_xor(vmax, 8));
        vmax = fmaxf(vmax, __shfl_xor(vmax, 16));
        vmax = fmaxf(vmax, __shfl_xor(vmax, 32));

        float vsum = (j == 0) ? expf(e_self - vmax) : 0.f;
#pragma unroll
        for (int c = 0; c < 8; c++){
            if (c >= nch) break;
            float t = (ex[c] > -1e37f) ? expf(ex[c] - vmax) : 0.f;
            ex[c] = t;
            vsum += t;
        }
        vsum += __shfl_xor(vsum, 8);
        vsum += __shfl_xor(vsum, 16);
        vsum += __shfl_xor(vsum, 32);
        float rden = 1.f / (vsum + EPS_F);

        int hw = lane >> 5, l32 = lane & 31, hd = l32 >> 2;
        float sa_reg = expf(e_self - vmax) * rden;
        float sa_b   = __shfl(sa_reg, hd);
        float asf    = hw ? 0.f : sa_b;

        float acc[8];
        {
            uint4 w = *(const uint4*)(h1b + (size_t)d * HC1 + l32 * 8);
            acc[0] = asf * __uint_as_float(w.x << 16);
            acc[1] = asf * __uint_as_float(w.x & 0xFFFF0000u);
            acc[2] = asf * __uint_as_float(w.y << 16);
            acc[3] = asf * __uint_as_float(w.y & 0xFFFF0000u);
            acc[4] = asf * __uint_as_float(w.z << 16);
            acc[5] = asf * __uint_as_float(w.z & 0xFFFF0000u);
            acc[6] = asf * __uint_as_float(w.w << 16);
            acc[7] = asf * __uint_as_float(w.w & 0xFFFF0000u);
        }

#pragma unroll
        for (int c = 0; c < 8; c++){
            if (c >= nch) break;
            float an = ex[c] * rden;
#pragma unroll
            for (int st = 0; st < 4; st++){
                int it = st * 2 + hw;
                int s  = __shfl(cv[c], it * 8);
                float a = __shfl(an, it * 8 + hd);
                uint4 w = *(const uint4*)(h1b + (size_t)s * HC1 + l32 * 8);
                acc[0] += a * __uint_as_float(w.x << 16);
                acc[1] += a * __uint_as_float(w.x & 0xFFFF0000u);
                acc[2] += a * __uint_as_float(w.y << 16);
                acc[3] += a * __uint_as_float(w.y & 0xFFFF0000u);
                acc[4] += a * __uint_as_float(w.z << 16);
                acc[5] += a * __uint_as_float(w.z & 0xFFFF0000u);
                acc[6] += a * __uint_as_float(w.w << 16);
                acc[7] += a * __uint_as_float(w.w & 0xFFFF0000u);
            }
        }
#pragma unroll
        for (int k = 0; k < 8; k++) acc[k] += __shfl_xor(acc[k], 32);

        if (lane < 32){
            float4 b0 = *(const float4*)(b1 + l32 * 8);
            float4 b4 = *(const float4*)(b1 + l32 * 8 + 4);
            uint4 o;
            o.x = (unsigned)f2bf(eluf(acc[0] + b0.x)) | ((unsigned)f2bf(eluf(acc[1] + b0.y)) << 16);
            o.y = (unsigned)f2bf(eluf(acc[2] + b0.z)) | ((unsigned)f2bf(eluf(acc[3] + b0.w)) << 16);
            o.z = (unsigned)f2bf(eluf(acc[4] + b4.x)) | ((unsigned)f2bf(eluf(acc[5] + b4.y)) << 16);
            o.w = (unsigned)f2bf(eluf(acc[6] + b4.z)) | ((unsigned)f2bf(eluf(acc[7] + b4.w)) << 16);
            *(uint4*)(outb + (size_t)d * HC1 + l32 * 8) = o;
        }
    } else {
        float vmax = e_self;
        for (int base = 0; base < deg; base += 8){
            int idx = base + j;
            if (idx < deg){
                int s = col[row0 + idx];
                vmax = fmaxf(vmax, lrelu(as1[s * NHEADS + h8] + adst));
            }
        }
        vmax = fmaxf(vmax, __shfl_xor(vmax, 8));
        vmax = fmaxf(vmax, __shfl_xor(vmax, 16));
        vmax = fmaxf(vmax, __shfl_xor(vmax, 32));

        float vsum = (j == 0) ? expf(e_self - vmax) : 0.f;
        for (int base = 0; base < deg; base += 8){
            int idx = base + j;
            if (idx < deg){
                int s = col[row0 + idx];
                vsum += expf(lrelu(as1[s * NHEADS + h8] + adst) - vmax);
            }
        }
        vsum += __shfl_xor(vsum, 8);
        vsum += __shfl_xor(vsum, 16);
        vsum += __shfl_xor(vsum, 32);
        float rden = 1.f / (vsum + EPS_F);

        int hw = lane >> 5, l32 = lane & 31, hd = l32 >> 2;
        float sa_reg = expf(e_self - vmax) * rden;
        float sa_b   = __shfl(sa_reg, hd);
        float asf    = hw ? 0.f : sa_b;

        float acc[8];
        {
            uint4 w = *(const uint4*)(h1b + (size_t)d * HC1 + l32 * 8);
            acc[0] = asf * __uint_as_float(w.x << 16);
            acc[1] = asf * __uint_as_float(w.x & 0xFFFF0000u);
            acc[2] = asf * __uint_as_float(w.y << 16);
            acc[3] = asf * __uint_as_float(w.y & 0xFFFF0000u);
            acc[4] = asf * __uint_as_float(w.z << 16);
            acc[5] = asf * __uint_as_float(w.z & 0xFFFF0000u);
            acc[6] = asf * __uint_as_float(w.w << 16);
            acc[7] = asf * __uint_as_float(w.w & 0xFFFF0000u);
        }

        for (int base = 0; base < deg; base += 8){
            int eidx = base + j;
            int cj = (eidx < deg) ? col[row0 + eidx] : d;
            float ae = (eidx < deg)
                     ? expf(lrelu(as1[cj * NHEADS + h8] + adst) - vmax) * rden : 0.f;
#pragma unroll
            for (int st = 0; st < 4; st++){
                int it = st * 2 + hw;
                int s  = __shfl(cj, it * 8);
                float a = __shfl(ae, it * 8 + hd);
                uint4 w = *(const uint4*)(h1b + (size_t)s * HC1 + l32 * 8);
                acc[0] += a * __uint_as_float(w.x << 16);
                acc[1] += a * __uint_as_float(w.x & 0xFFFF0000u);
                acc[2] += a * __uint_as_float(w.y << 16);
                acc[3] += a * __uint_as_float(w.y & 0xFFFF0000u);
                acc[4] += a * __uint_as_float(w.z << 16);
                acc[5] += a * __uint_as_float(w.z & 0xFFFF0000u);
                acc[6] += a * __uint_as_float(w.w << 16);
                acc[7] += a * __uint_as_float(w.w & 0xFFFF0000u);
            }
        }
#pragma unroll
        for (int k = 0; k < 8; k++) acc[k] += __shfl_xor(acc[k], 32);

        if (lane < 32){
            float4 b0 = *(const float4*)(b1 + l32 * 8);
            float4 b4 = *(const float4*)(b1 + l32 * 8 + 4);
            uint4 o;
            o.x = (unsigned)f2bf(eluf(acc[0] + b0.x)) | ((unsigned)f2bf(eluf(acc[1] + b0.y)) << 16);
            o.y = (unsigned)f2bf(eluf(acc[2] + b0.z)) | ((unsigned)f2bf(eluf(acc[3] + b0.w)) << 16);
            o.z = (unsigned)f2bf(eluf(acc[4] + b4.x)) | ((unsigned)f2bf(eluf(acc[5] + b4.y)) << 16);
            o.w = (unsigned)f2bf(eluf(acc[6] + b4.z)) | ((unsigned)f2bf(eluf(acc[7] + b4.w)) << 16);
            *(uint4*)(outb + (size_t)d * HC1 + l32 * 8) = o;
        }
    }
}

// ---------------- GAT layer 2 aggregation (4 gathers in flight) ----------------
__global__ void gat2_agg_k(const u16* __restrict__ h2b, const float* __restrict__ as2,
                           const float* __restrict__ ad2, const int* __restrict__ rowptr,
                           const int* __restrict__ col, const float* __restrict__ b2,
                           float* __restrict__ emb){
    int lane = threadIdx.x & 63, wid = threadIdx.x >> 6;
    int d = blockIdx.x * 4 + wid;
    int row0 = rowptr[d];
    int deg  = rowptr[d + 1] - row0;

    float adst = ad2[d];
    float e_self = lrelu(as2[d] + adst);

    if (deg <= 64){
        int sv = (lane < deg) ? col[row0 + lane] : d;
        float e_lane = (lane < deg) ? lrelu(as2[sv] + adst) : -3e38f;
        float vmax = fmaxf(e_self, e_lane);
        for (int m = 1; m < 64; m <<= 1) vmax = fmaxf(vmax, __shfl_xor(vmax, m));
        float exl = (lane < deg) ? expf(e_lane - vmax) : 0.f;
        float vsum = exl + ((lane == 0) ? expf(e_self - vmax) : 0.f);
        for (int m = 1; m < 64; m <<= 1) vsum += __shfl_xor(vsum, m);
        float rden = 1.f / (vsum + EPS_F);
        float alpha_l = exl * rden;               // 0 for lanes >= deg
        float sa = expf(e_self - vmax) * rden;

        int q = lane >> 4, c4 = (lane & 15) * 4;
        float a0 = (q == 0) ? sa : 0.f;
        float4 acc;
        {
            ushort4 u = *(const ushort4*)(h2b + (size_t)d * OUTC + c4);
            acc = make_float4(a0 * bf2f(u.x), a0 * bf2f(u.y), a0 * bf2f(u.z), a0 * bf2f(u.w));
        }
        for (int it0 = 0; it0 < deg; it0 += 16){
            int s_arr[4]; float a_arr[4];
#pragma unroll
            for (int k = 0; k < 4; k++){
                int itc = min(it0 + k * 4 + q, 63);
                s_arr[k] = __shfl(sv, itc);
                a_arr[k] = __shfl(alpha_l, itc);
            }
            ushort4 u_arr[4];
#pragma unroll
            for (int k = 0; k < 4; k++)
                u_arr[k] = *(const ushort4*)(h2b + (unsigned)s_arr[k] * OUTC + c4);
#pragma unroll
            for (int k = 0; k < 4; k++){
                float a = a_arr[k]; ushort4 u = u_arr[k];
                acc.x += a * bf2f(u.x); acc.y += a * bf2f(u.y);
                acc.z += a * bf2f(u.z); acc.w += a * bf2f(u.w);
            }
        }
        acc.x += __shfl_xor(acc.x, 16); acc.y += __shfl_xor(acc.y, 16);
        acc.z += __shfl_xor(acc.z, 16); acc.w += __shfl_xor(acc.w, 16);
        acc.x += __shfl_xor(acc.x, 32); acc.y += __shfl_xor(acc.y, 32);
        acc.z += __shfl_xor(acc.z, 32); acc.w += __shfl_xor(acc.w, 32);
        if (lane < 16){
            float4 bb = *(const float4*)(b2 + c4);
            float4 o = make_float4(acc.x + bb.x, acc.y + bb.y, acc.z + bb.z, acc.w + bb.w);
            *(float4*)(emb + (size_t)d * OUTC + c4) = o;
        }
    } else {
        float vmax = e_self;
        for (int base = 0; base < deg; base += 64){
            int idx = base + lane;
            if (idx < deg){
                int s = col[row0 + idx];
                vmax = fmaxf(vmax, lrelu(as2[s] + adst));
            }
        }
        for (int m = 1; m < 64; m <<= 1) vmax = fmaxf(vmax, __shfl_xor(vmax, m));
        float vsum = (lane == 0) ? expf(e_self - vmax) : 0.f;
        for (int base = 0; base < deg; base += 64){
            int idx = base + lane;
            if (idx < deg){
                int s = col[row0 + idx];
                vsum += expf(lrelu(as2[s] + adst) - vmax);
            }
        }
        for (int m = 1; m < 64; m <<= 1) vsum += __shfl_xor(vsum, m);
        float rden = 1.f / (vsum + EPS_F);
        float alpha = expf(e_self - vmax) * rden;
        float acc = alpha * bf2f(h2b[(size_t)d * OUTC + lane]);
        for (int idx = 0; idx < deg; idx++){
            int s = col[row0 + idx];
            float a = expf(lrelu(as2[s] + adst) - vmax) * rden;
            acc += a * bf2f(h2b[(size_t)s * OUTC + lane]);
        }
        emb[(size_t)d * OUTC + lane] = acc + b2[lane];
    }
}

// ---------------- MLP head + softmax via MFMA ----------------
__global__ void mlp_mfma_k(const float* __restrict__ emb, const u16* __restrict__ W1mt,
                           const float* __restrict__ bm1, const u16* __restrict__ W2mt,
                           const float* __restrict__ bm2, float* __restrict__ sout){
    __shared__ u16 hid[4][16][136];
    int lane = threadIdx.x & 63, wid = threadIdx.x >> 6;
    int ln = lane & 15, quad = lane >> 4;
    int m0 = blockIdx.x * 64 + wid * 16;
    int arow = m0 + ln; if (arow >= NNODES) arow = NNODES - 1;

    bf16x8 a[2];
#pragma unroll
    for (int kt = 0; kt < 2; kt++){
        const float* ap = emb + (size_t)arow * OUTC + kt * 32 + quad * 8;
        float4 v0 = *(const float4*)ap;
        float4 v1 = *(const float4*)(ap + 4);
        bf16x8 t;
        t[0] = f2bf_s(v0.x); t[1] = f2bf_s(v0.y); t[2] = f2bf_s(v0.z); t[3] = f2bf_s(v0.w);
        t[4] = f2bf_s(v1.x); t[5] = f2bf_s(v1.y); t[6] = f2bf_s(v1.z); t[7] = f2bf_s(v1.w);
        a[kt] = t;
    }

    f32x4 acc[8];
#pragma unroll
    for (int nt = 0; nt < 8; nt++) acc[nt] = (f32x4){0.f, 0.f, 0.f, 0.f};
#pragma unroll
    for (int kt = 0; kt < 2; kt++){
#pragma unroll
        for (int nt = 0; nt < 8; nt++){
            bf16x8 b = *(const bf16x8*)(W1mt + (size_t)(nt * 16 + ln) * OUTC + kt * 32 + quad * 8);
            acc[nt] = __builtin_amdgcn_mfma_f32_16x16x32_bf16(a[kt], b, acc[nt], 0, 0, 0);
        }
    }

#pragma unroll
    for (int nt = 0; nt < 8; nt++){
        float bb = bm1[nt * 16 + ln];
#pragma unroll
        for (int i = 0; i < 4; i++){
            float h = fmaxf(acc[nt][i] + bb, 0.f);
            hid[wid][quad * 4 + i][nt * 16 + ln] = f2bf(h);
        }
    }

    f32x4 acc2 = (f32x4){0.f, 0.f, 0.f, 0.f};
#pragma unroll
    for (int kt = 0; kt < 4; kt++){
        bf16x8 ah = *(const bf16x8*)&hid[wid][ln][kt * 32 + quad * 8];
        bf16x8 bw = *(const bf16x8*)(W2mt + (size_t)ln * 128 + kt * 32 + quad * 8);
        acc2 = __builtin_amdgcn_mfma_f32_16x16x32_bf16(ah, bw, acc2, 0, 0, 0);
    }

    float bcl = bm2[ln];
#pragma unroll
    for (int i = 0; i < 4; i++){
        int r = m0 + quad * 4 + i;
        float lg = acc2[i] + bcl;
        float m = lg;
        m = fmaxf(m, __shfl_xor(m, 1));
        m = fmaxf(m, __shfl_xor(m, 2));
        m = fmaxf(m, __shfl_xor(m, 4));
        m = fmaxf(m, __shfl_xor(m, 8));
        float ex = expf(lg - m);
        float s = ex;
        s += __shfl_xor(s, 1);
        s += __shfl_xor(s, 2);
        s += __shfl_xor(s, 4);
        s += __shfl_xor(s, 8);
        if (r < NNODES) sout[(size_t)r * NK + ln] = ex / s;
    }
}

// ---------------- launcher ----------------
extern "C" void kernel_launch(void* const* d_in, const int* in_sizes, int n_in,
                              void* d_out, int out_size, void* d_ws, size_t ws_size,
                              hipStream_t stream){
    const float* x      = (const float*)d_in[0];
    const int*   ei     = (const int*)d_in[1];
    const int*   srcv   = ei;
    const int*   dstv   = ei + NEDGES;
    const float* W1     = (const float*)d_in[2];
    const float* att_s1 = (const float*)d_in[3];
    const float* att_d1 = (const float*)d_in[4];
    const float* b1     = (const float*)d_in[5];
    const float* W2     = (const float*)d_in[6];
    const float* att_s2 = (const float*)d_in[7];
    const float* att_d2 = (const float*)d_in[8];
    const float* b2     = (const float*)d_in[9];
    const float* Wm1    = (const float*)d_in[10];
    const float* bm1    = (const float*)d_in[11];
    const float* Wm2    = (const float*)d_in[12];
    const float* bm2    = (const float*)d_in[13];

    float* out     = (float*)d_out;                     // s: [N,16]
    float* emb_out = out + (size_t)NNODES * NK;         // embeddings: [N,64]

    u16* h1b   = (u16*)d_ws;                            // N*256
    u16* hL1b  = h1b  + (size_t)NNODES * HC1;           // N*256
    u16* h2b   = hL1b + (size_t)NNODES * HC1;           // N*64
    u16* W1t   = h2b  + (size_t)NNODES * OUTC;          // 256*128
    u16* W2t   = W1t + 256 * 128;                       // 64*256
    u16* W1mt  = W2t + 64 * 256;                        // 128*64
    u16* W2mt  = W1mt + 128 * 64;                       // 16*128
    float* as1 = (float*)(W2mt + 16 * 128);             // N*8
    float* ad1 = as1 + (size_t)NNODES * NHEADS;         // N*8
    float* as2 = ad1 + (size_t)NNODES * NHEADS;         // N
    float* ad2 = as2 + NNODES;                          // N
    int* deg    = (int*)(ad2 + NNODES);                 // N   (deg+fillc adjacent -> 1 memset)
    int* fillc  = deg + NNODES;                         // N
    int* rowptr = fillc + NNODES;                       // N+1
    int* bsum   = rowptr + NNODES + 1;                  // 256
    int* colv   = bsum + 256;                           // E

    hipMemsetAsync(deg, 0, 2 * NNODES * sizeof(int), stream);

    const int NB = (NNODES + 255) / 256;   // 196

    count_deg_tw_k<<<EB + TB, 256, 0, stream>>>(dstv, deg, W1, W1t, W2, W2t, Wm1, W1mt, Wm2, W2mt);
    blocksum_k<<<NB, 256, 0, stream>>>(deg, bsum);
    scan_write_k<<<NB, 256, 0, stream>>>(deg, bsum, rowptr);
    fill_csr_k<<<(NEDGES + 255) / 256, 256, 0, stream>>>(srcv, dstv, rowptr, fillc, colv);

    const int MB = (NNODES + 63) / 64;   // 782

    l1_k<<<dim3(MB, 2), 256, 0, stream>>>(x, W1t, att_s1, att_d1, h1b, as1, ad1);
    gat1_agg_k<<<NNODES / 4, 256, 0, stream>>>(h1b, as1, ad1, rowptr, colv, b1, hL1b);

    l2_k<<<MB, 256, 0, stream>>>(hL1b, W2t, att_s2, att_d2, h2b, as2, ad2);
    gat2_agg_k<<<NNODES / 4, 256, 0, stream>>>(h2b, as2, ad2, rowptr, colv, b2, emb_out);

    mlp_mfma_k<<<MB, 256, 0, stream>>>(emb_out, W1mt, bm1, W2mt, bm2, out);
}